// Round 6
// baseline (172.026 us; speedup 1.0000x reference)
//
#include <hip/hip_runtime.h>

// ---------------------------------------------------------------------------
// LargeWindowAttention on MI355X (gfx950)
// pq(fused pool+q-relayout) -> ln -> mix(MFMA) -> QKV GEMMs (bf16 MFMA) ->
// batched window attention (swapped-QK^T, barrier-free, reg-resident softmax)
// -> out GEMM -> relayout.
// ---------------------------------------------------------------------------

typedef __bf16 bf16;
typedef __bf16 bf16x2 __attribute__((ext_vector_type(2)));
typedef __bf16 bf16x4 __attribute__((ext_vector_type(4)));
typedef __bf16 bf16x8 __attribute__((ext_vector_type(8)));
typedef float f32x4 __attribute__((ext_vector_type(4)));
typedef unsigned int u32x4 __attribute__((ext_vector_type(4)));

#define MFMA(a, b, c) __builtin_amdgcn_mfma_f32_16x16x32_bf16(a, b, c, 0, 0, 0)

__device__ __forceinline__ void gll16(const void* g, void* l) {
  __builtin_amdgcn_global_load_lds((const __attribute__((address_space(1))) void*)g,
                                   (__attribute__((address_space(3))) void*)l, 16, 0, 0);
}

__device__ __forceinline__ unsigned int cvtpk(float a, float b) {
  unsigned int r;
  asm("v_cvt_pk_bf16_f32 %0, %1, %2" : "=v"(r) : "v"(a), "v"(b));
  return r;
}

// ---------------------------------------------------------------------------
__global__ void k_wconv(const float* __restrict__ in_w, const float* __restrict__ out_w,
                        bf16* __restrict__ wib, bf16* __restrict__ wob) {
  int i = blockIdx.x * blockDim.x + threadIdx.x;
  const int n1 = (1536 * 512) / 4;
  float4 v;
  bf16* dst;
  if (i < n1) { v = ((const float4*)in_w)[i];      dst = wib + (size_t)i * 4; }
  else        { v = ((const float4*)out_w)[i - n1]; dst = wob + (size_t)(i - n1) * 4; }
  dst[0] = (bf16)v.x; dst[1] = (bf16)v.y; dst[2] = (bf16)v.z; dst[3] = (bf16)v.w;
}

// ---------------------------------------------------------------------------
// Fused: read x once -> pooled xp2t[y2][x2][c] fp32 + q relayout bf16.
__global__ __launch_bounds__(256) void k_pq(const float* __restrict__ x,
                                            float* __restrict__ xp2t,
                                            bf16* __restrict__ qb) {
  __shared__ float xs[2][64][133];
  const int y2 = blockIdx.x, c0 = blockIdx.y * 64, t = threadIdx.x;
  #pragma unroll
  for (int it = 0; it < 16; ++it) {
    int flat = it * 256 + t;
    int ci = flat >> 6, rest = flat & 63;
    int yb = rest >> 5, xq = rest & 31;
    float4 v = *(const float4*)(x + (size_t)(c0 + ci) * 16384 +
                                (size_t)(2 * y2 + yb) * 128 + xq * 4);
    float* d = &xs[yb][ci][xq * 4];
    d[0] = v.x; d[1] = v.y; d[2] = v.z; d[3] = v.w;
  }
  __syncthreads();
  #pragma unroll
  for (int it = 0; it < 16; ++it) {
    int flat = it * 256 + t;
    int x2 = flat >> 6, ci = flat & 63;
    float s = xs[0][ci][2 * x2] + xs[0][ci][2 * x2 + 1] +
              xs[1][ci][2 * x2] + xs[1][ci][2 * x2 + 1];
    xp2t[(size_t)(y2 * 64 + x2) * 512 + c0 + ci] = 0.25f * s;
  }
  #pragma unroll
  for (int yb = 0; yb < 2; ++yb) {
    const int Y = 2 * y2 + yb;
    const int hy = Y >> 3, py = Y & 7;
    #pragma unroll
    for (int it = 0; it < 32; ++it) {
      int flat = it * 256 + t;
      int X = flat >> 6, ci = flat & 63;
      int l = py * 8 + (X & 7), s = hy * 16 + (X >> 3);
      qb[((size_t)l * 256 + s) * 512 + c0 + ci] = (bf16)xs[yb][ci][X];
    }
  }
}

// ---------------------------------------------------------------------------
__global__ __launch_bounds__(512) void k_ln(const float* __restrict__ xp2t,
                                            const float* __restrict__ lnw,
                                            const float* __restrict__ lnb,
                                            bf16* __restrict__ T) {
  __shared__ bf16 Tt[512][24];
  const int s = blockIdx.x, qt = blockIdx.y;
  const int wy = s >> 4, wx = s & 15;
  const int t = threadIdx.x, wv = t >> 6, ln = t & 63;

  float wl[8], bl[8];
  #pragma unroll
  for (int k = 0; k < 8; ++k) { wl[k] = lnw[k * 64 + ln]; bl[k] = lnb[k * 64 + ln]; }

  float v[2][8], mu_[2], rs_[2];
  #pragma unroll
  for (int p = 0; p < 2; ++p) {
    const int l = qt * 16 + wv * 2 + p;
    const int py = l >> 3, px = l & 7;
    const int y2 = wy * 4 - 2 + py, x2 = wx * 4 - 2 + px;
    const bool inb = (y2 >= 0) && (y2 < 64) && (x2 >= 0) && (x2 < 64);
    const float* src = xp2t + (size_t)(y2 * 64 + x2) * 512;
    float sum = 0.f, ssq = 0.f;
    #pragma unroll
    for (int k = 0; k < 8; ++k) {
      float xv = 0.f;
      if (inb) xv = src[k * 64 + ln];
      v[p][k] = xv; sum += xv; ssq += xv * xv;
    }
    #pragma unroll
    for (int off = 1; off < 64; off <<= 1) {
      sum += __shfl_xor(sum, off);
      ssq += __shfl_xor(ssq, off);
    }
    float mu = sum * (1.f / 512.f);
    mu_[p] = mu;
    rs_[p] = rsqrtf(ssq * (1.f / 512.f) - mu * mu + 1e-6f);
  }
  #pragma unroll
  for (int k = 0; k < 8; ++k) {
    const int c = k * 64 + ln;
    bf16x2 u;
    u.x = (bf16)((v[0][k] - mu_[0]) * rs_[0] * wl[k] + bl[k]);
    u.y = (bf16)((v[1][k] - mu_[1]) * rs_[1] * wl[k] + bl[k]);
    *(bf16x2*)(&Tt[c][wv * 2]) = u;
  }
  __syncthreads();
  #pragma unroll
  for (int it = 0; it < 2; ++it) {
    int flat = it * 512 + t;
    int c = flat >> 1, ch = flat & 1;
    bf16x8 u = *(const bf16x8*)(&Tt[c][ch * 8]);
    *(bf16x8*)(T + ((size_t)s * 512 + c) * 64 + qt * 16 + ch * 8) = u;
  }
}

// ---------------------------------------------------------------------------
__global__ __launch_bounds__(256) void k_mix(const bf16* __restrict__ T,
                                             const float* __restrict__ mix_w,
                                             const float* __restrict__ mix_b,
                                             bf16* __restrict__ ctx) {
  const int t = threadIdx.x, wv = t >> 6, ln = t & 63;
  const int s = blockIdx.x, hg = blockIdx.y;
  const int h = hg * 4 + wv;
  const int q = ln >> 4, r = ln & 15;

  bf16x8 a[4][2];
  #pragma unroll
  for (int m = 0; m < 4; ++m) {
    #pragma unroll
    for (int ks = 0; ks < 2; ++ks) {
      const int rm = m * 16 + r;
      const float* wsrc = mix_w + ((size_t)h * 64 + rm) * 64 + ks * 32 + q * 8;
      bf16x8 pk;
      #pragma unroll
      for (int e = 0; e < 8; ++e) {
        int l = ks * 32 + q * 8 + e;
        float w = wsrc[e] + (rm == l ? 1.f : 0.f);
        pk[e] = (bf16)w;
      }
      a[m][ks] = pk;
    }
  }
  const bf16* Tb = T + ((size_t)s * 512 + h * 64) * 64;
  bf16x8 b[4][2];
  #pragma unroll
  for (int n = 0; n < 4; ++n) {
    #pragma unroll
    for (int ks = 0; ks < 2; ++ks)
      b[n][ks] = *(const bf16x8*)(Tb + (size_t)(n * 16 + r) * 64 + ks * 32 + q * 8);
  }
  f32x4 acc[4][4] = {};
  #pragma unroll
  for (int ks = 0; ks < 2; ++ks) {
    #pragma unroll
    for (int m = 0; m < 4; ++m) {
      #pragma unroll
      for (int n = 0; n < 4; ++n) acc[m][n] = MFMA(a[m][ks], b[n][ks], acc[m][n]);
    }
  }
  #pragma unroll
  for (int m = 0; m < 4; ++m) {
    #pragma unroll
    for (int j = 0; j < 4; ++j) {
      const int rm = m * 16 + q * 4 + j;
      const float bias = mix_b[h * 64 + rm];
      #pragma unroll
      for (int n = 0; n < 4; ++n)
        ctx[((size_t)rm * 256 + s) * 512 + h * 64 + n * 16 + r] =
            (bf16)(acc[m][n][j] + bias);
    }
  }
}

// ---------------------------------------------------------------------------
// GEMM C[M,N] = A[M,K=512] @ B[N,K=512]^T + bias, bf16 in, fp32 accum.
template <int MODE>
__global__ __launch_bounds__(256, 4) void k_gemm(const bf16* __restrict__ A,
                                                 const bf16* __restrict__ B,
                                                 const float* __restrict__ bias,
                                                 bf16* __restrict__ O0,
                                                 bf16* __restrict__ O1) {
  __shared__ bf16 As[8192];
  __shared__ bf16 Bs[8192];
  const int t = threadIdx.x, wv = t >> 6, ln = t & 63;
  const int bm = blockIdx.x, bn = blockIdx.y;
  const int wm = wv >> 1, wn = wv & 1;
  const int q = ln >> 4, r = ln & 15;
  f32x4 acc[4][4] = {};

  const int srow = wv * 8 + (ln >> 3);
  const int swzc = (ln & 7) ^ (ln >> 3);
  const char* ga = (const char*)A + ((size_t)(bm * 128 + srow) * 512) * 2 + swzc * 16;
  const char* gb = (const char*)B + ((size_t)(bn * 128 + srow) * 512) * 2 + swzc * 16;

  for (int k0 = 0; k0 < 512; k0 += 64) {
    #pragma unroll
    for (int i = 0; i < 4; ++i) {
      gll16(ga + (size_t)i * 32 * 1024 + k0 * 2, As + i * 2048 + wv * 512);
      gll16(gb + (size_t)i * 32 * 1024 + k0 * 2, Bs + i * 2048 + wv * 512);
    }
    __syncthreads();
    #pragma unroll
    for (int ks = 0; ks < 2; ++ks) {
      bf16x8 af[4], bfr[4];
      #pragma unroll
      for (int m = 0; m < 4; ++m)
        af[m] = *(const bf16x8*)(As + (wm * 64 + m * 16 + r) * 64 +
                                 (((ks * 4 + q) ^ (r & 7)) * 8));
      #pragma unroll
      for (int n = 0; n < 4; ++n)
        bfr[n] = *(const bf16x8*)(Bs + (wn * 64 + n * 16 + r) * 64 +
                                  (((ks * 4 + q) ^ (r & 7)) * 8));
      #pragma unroll
      for (int m = 0; m < 4; ++m) {
        #pragma unroll
        for (int n = 0; n < 4; ++n) acc[m][n] = MFMA(af[m], bfr[n], acc[m][n]);
      }
    }
    __syncthreads();
  }

  const int r0 = bm * 128 + wm * 64 + q * 4;
  const int c0 = bn * 128 + wn * 64 + r;
  #pragma unroll
  for (int m = 0; m < 4; ++m) {
    const int rg0 = r0 + m * 16;
    #pragma unroll
    for (int n = 0; n < 4; ++n) {
      const int cg = c0 + n * 16;
      const float bv = bias[cg];
      if constexpr (MODE == 2) {
        #pragma unroll
        for (int j = 0; j < 4; ++j)
          O0[(size_t)(rg0 + j) * 512 + cg] = (bf16)(acc[m][n][j] + bv);
      } else if constexpr (MODE == 0) {
        const int li = rg0 >> 8;
        #pragma unroll
        for (int j = 0; j < 4; ++j) {
          int sp = (rg0 + j) & 255;
          O0[(((size_t)li * 8 + (cg >> 6)) * 256 + sp) * 64 + (cg & 63)] =
              (bf16)(acc[m][n][j] + bv);
        }
      } else {  // MODE 1
        const int li = rg0 >> 8;
        if (cg < 512) {
          #pragma unroll
          for (int j = 0; j < 4; ++j) {
            int sp = (rg0 + j) & 255;
            O0[(((size_t)li * 8 + (cg >> 6)) * 256 + sp) * 64 + (cg & 63)] =
                (bf16)(acc[m][n][j] + bv);
          }
        } else {
          const int e = cg - 512, hh = e >> 6, d = e & 63;
          const int sp = rg0 & 255;
          bf16x4 pk;
          #pragma unroll
          for (int j = 0; j < 4; ++j) pk[j] = (bf16)(acc[m][n][j] + bv);
          *(bf16x4*)(&O1[(((size_t)li * 8 + hh) * 64 + d) * 256 + sp]) = pk;
        }
      }
    }
  }
}

// ---------------------------------------------------------------------------
// Attention per (l,h,s-tile 64): swapped QK^T (S^T = mfma(K,Q)) so each lane
// owns ONE s-row; softmax = in-lane reduce + 2 shfl; P rebuilt in-register
// via cvt_pk + 2-stage xor16/xor32 exchange; PV = O^T = mfma(V,P).
// ZERO LDS, ZERO barriers. Flash over t in 2 halves of 128.
__global__ __launch_bounds__(256, 4) void k_attn(const bf16* __restrict__ Qa,
                                                 const bf16* __restrict__ Ka,
                                                 const bf16* __restrict__ Vt,
                                                 bf16* __restrict__ Oa) {
  const int t = threadIdx.x, wv = t >> 6, ln = t & 63;
  const int q = ln >> 4, r = ln & 15;
  const int bid = blockIdx.x;
  const int st = (bid >> 3) & 3;                 // siblings share bid%8 -> XCD
  const int lh = (bid & 7) | ((bid >> 5) << 3);
  const int s0 = st * 64;
  const size_t base = (size_t)lh * (256 * 64);
  const bf16* __restrict__ Qlh = Qa + base;
  const bf16* __restrict__ Klh = Ka + base;
  const bf16* __restrict__ Vlh = Vt + base;
  const float SC = 0.125f * 1.4426950408889634f;

  // Q B-frags: rows s = s0 + wv*16 + r (lane's own row)
  bf16x8 bq[2];
  #pragma unroll
  for (int ks = 0; ks < 2; ++ks)
    bq[ks] = *(const bf16x8*)(Qlh + (size_t)(s0 + wv * 16 + r) * 64 + ks * 32 + q * 8);

  f32x4 ao[4] = {};       // O^T accum: lane holds O[s=own][d = md*16 + q*4 + jj]
  float m_run = 0.f, l_run = 0.f;

  #pragma unroll
  for (int h = 0; h < 2; ++h) {
    // S^T: rows t (lane holds t = h*128 + m*16 + q*4 + jj), col s = own row
    f32x4 sa[8];
    #pragma unroll
    for (int m = 0; m < 8; ++m) sa[m] = (f32x4){0.f, 0.f, 0.f, 0.f};
    #pragma unroll
    for (int m = 0; m < 8; ++m) {
      const bf16* kb = Klh + (size_t)(h * 128 + m * 16 + r) * 64 + q * 8;
      bf16x8 a0 = *(const bf16x8*)(kb);
      bf16x8 a1 = *(const bf16x8*)(kb + 32);
      sa[m] = MFMA(a0, bq[0], sa[m]);
      sa[m] = MFMA(a1, bq[1], sa[m]);
    }

    // softmax over t for this lane's s: 31 in-lane + 2 shfl (max), same for sum
    float mx = sa[0][0];
    #pragma unroll
    for (int m = 0; m < 8; ++m) {
      #pragma unroll
      for (int j = 0; j < 4; ++j) mx = fmaxf(mx, sa[m][j]);
    }
    mx = fmaxf(mx, __shfl_xor(mx, 16));
    mx = fmaxf(mx, __shfl_xor(mx, 32));
    const float mnew = (h == 0) ? mx : fmaxf(m_run, mx);
    const float mb = mnew * SC;
    float sum = 0.f;
    #pragma unroll
    for (int m = 0; m < 8; ++m) {
      #pragma unroll
      for (int j = 0; j < 4; ++j) {
        float p = exp2f(sa[m][j] * SC - mb);
        sa[m][j] = p;
        sum += p;
      }
    }
    sum += __shfl_xor(sum, 16);
    sum += __shfl_xor(sum, 32);
    if (h == 0) {
      m_run = mnew; l_run = sum;
    } else {
      float scale = exp2f(m_run * SC - mb);
      l_run = l_run * scale + sum;
      m_run = mnew;
      #pragma unroll
      for (int md = 0; md < 4; ++md) {
        #pragma unroll
        for (int j = 0; j < 4; ++j) ao[md][j] *= scale;
      }
    }

    // pack P to bf16 pairs: E = m-even {P2[2j].u0,.u1}, O = m-odd
    unsigned int E[8], O[8];
    #pragma unroll
    for (int j = 0; j < 4; ++j) {
      E[2 * j]     = cvtpk(sa[2 * j][0], sa[2 * j][1]);
      E[2 * j + 1] = cvtpk(sa[2 * j][2], sa[2 * j][3]);
      O[2 * j]     = cvtpk(sa[2 * j + 1][0], sa[2 * j + 1][1]);
      O[2 * j + 1] = cvtpk(sa[2 * j + 1][2], sa[2 * j + 1][3]);
    }
    // 2-stage q-lane exchange (verified network):
    // needs: q0<-E(q'0,q'1), q1<-E(q'2,q'3), q2<-O(q'0,q'1), q3<-O(q'2,q'3)
    unsigned int R1[8], R2[8];
    #pragma unroll
    for (int i = 0; i < 8; ++i)
      R1[i] = (unsigned int)__shfl_xor((int)((q < 2) ? O[i] : E[i]), 32);
    #pragma unroll
    for (int i = 0; i < 8; ++i) {
      unsigned int keep = (q < 2) ? E[i] : O[i];
      R2[i] = (unsigned int)__shfl_xor((int)((q == 0 || q == 3) ? R1[i] : keep), 16);
    }

    // PV: O^T accum; P-frag slot ks = {partA(2ks,2ks+1), partB(2ks,2ks+1)}
    #pragma unroll
    for (int ks = 0; ks < 4; ++ks) {
      unsigned int a0 = (q == 0) ? E[2 * ks] : (q == 2) ? R1[2 * ks] : R2[2 * ks];
      unsigned int a1 = (q == 0) ? E[2 * ks + 1] : (q == 2) ? R1[2 * ks + 1] : R2[2 * ks + 1];
      unsigned int b0 = (q == 3) ? O[2 * ks] : (q == 1) ? R1[2 * ks] : R2[2 * ks];
      unsigned int b1 = (q == 3) ? O[2 * ks + 1] : (q == 1) ? R1[2 * ks + 1] : R2[2 * ks + 1];
      u32x4 uu = (u32x4){a0, a1, b0, b1};
      bf16x8 pf = __builtin_bit_cast(bf16x8, uu);
      #pragma unroll
      for (int md = 0; md < 4; ++md) {
        bf16x8 vf = *(const bf16x8*)(Vlh + (size_t)(md * 16 + r) * 256 +
                                     h * 128 + ks * 32 + q * 8);
        ao[md] = MFMA(vf, pf, ao[md]);
      }
    }
  }

  // epilogue: per-lane scale by 1/l, 4 x 8B stores (row s = own, d chunks)
  const float rr = 1.f / l_run;
  bf16* dst = Oa + ((size_t)(lh >> 3) * 256 + s0 + wv * 16 + r) * 512 +
              (lh & 7) * 64 + q * 4;
  #pragma unroll
  for (int md = 0; md < 4; ++md) {
    uint2 pk2;
    pk2.x = cvtpk(ao[md][0] * rr, ao[md][1] * rr);
    pk2.y = cvtpk(ao[md][2] * rr, ao[md][3] * rr);
    *(uint2*)(dst + md * 16) = pk2;
  }
}

// ---------------------------------------------------------------------------
__global__ void k_orelay(const bf16* __restrict__ o_tmp, float* __restrict__ out) {
  __shared__ bf16 buf[64][130];
  const int hy = blockIdx.x, py = blockIdx.y, e0 = blockIdx.z * 64, t = threadIdx.x;
  #pragma unroll
  for (int i = 0; i < 32; ++i) {
    int flat = i * 256 + t;
    int r = flat >> 6, e = flat & 63;
    int px = r >> 4, hx = r & 15;
    buf[e][hx * 8 + px] =
        o_tmp[((size_t)(py * 8 + px) * 256 + hy * 16 + hx) * 512 + e0 + e];
  }
  __syncthreads();
  const int Y = hy * 8 + py;
  #pragma unroll
  for (int i = 0; i < 32; ++i) {
    int flat = i * 256 + t;
    int e = flat >> 7, X = flat & 127;
    out[(size_t)(e0 + e) * 16384 + (size_t)Y * 128 + X] = (float)buf[e][X];
  }
}

// ---------------------------------------------------------------------------
extern "C" void kernel_launch(void* const* d_in, const int* in_sizes, int n_in,
                              void* d_out, int out_size, void* d_ws, size_t ws_size,
                              hipStream_t stream) {
  const float* x     = (const float*)d_in[0];
  const float* ln_w  = (const float*)d_in[1];
  const float* ln_b  = (const float*)d_in[2];
  const float* mix_w = (const float*)d_in[3];
  const float* mix_b = (const float*)d_in[4];
  const float* in_w  = (const float*)d_in[5];
  const float* in_b  = (const float*)d_in[6];
  const float* out_w = (const float*)d_in[7];
  const float* out_b = (const float*)d_in[8];
  float* out = (float*)d_out;
  char* ws = (char*)d_ws;

  const size_t MB = 1u << 20;
  float* xp2t = (float*)(ws);                    // [0,8)   pq -> ln
  bf16* qb    = (bf16*)(ws + 8 * MB);            // [8,24)  pq -> gemm0
  bf16* Tn    = (bf16*)(ws + 24 * MB);           // [24,40) ln -> mix
  bf16* ctxb  = (bf16*)(ws + 40 * MB);           // [40,56) mix -> gemm1
  bf16* Qa    = (bf16*)(ws + 56 * MB);           // [56,72) gemm0 -> attn
  bf16* Ka    = (bf16*)(ws);                     // [0,16)  gemm1 -> attn
  bf16* Vt    = (bf16*)(ws + 16 * MB);           // [16,32) gemm1 -> attn
  bf16* oatt  = (bf16*)(ws + 32 * MB);           // [32,48) attn -> gemm2
  bf16* otmp  = (bf16*)(ws + 48 * MB);           // [48,64) gemm2 -> orelay
  bf16* wib   = (bf16*)(ws + 72 * MB);
  bf16* wob   = (bf16*)(ws + 72 * MB + 1572864);

  k_wconv<<<1024, 256, 0, stream>>>(in_w, out_w, wib, wob);
  k_pq<<<dim3(64, 8), 256, 0, stream>>>(x, xp2t, qb);
  k_ln<<<dim3(256, 4), 512, 0, stream>>>(xp2t, ln_w, ln_b, Tn);
  k_mix<<<dim3(256, 2), 256, 0, stream>>>(Tn, mix_w, mix_b, ctxb);
  k_gemm<0><<<dim3(128, 4), 256, 0, stream>>>(qb, wib, in_b, Qa, nullptr);
  k_gemm<1><<<dim3(128, 8), 256, 0, stream>>>(ctxb, wib + 512 * 512, in_b + 512, Ka, Vt);
  k_attn<<<2048, 256, 0, stream>>>(Qa, Ka, Vt, oatt);
  k_gemm<2><<<dim3(128, 4), 256, 0, stream>>>(oatt, wob, out_b, otmp, nullptr);
  k_orelay<<<dim3(16, 8, 8), 256, 0, stream>>>(otmp, out);
}

// Round 7
// 148.849 us; speedup vs baseline: 1.1557x; 1.1557x over previous
//
#include <hip/hip_runtime.h>

// ---------------------------------------------------------------------------
// LargeWindowAttention on MI355X (gfx950)
// pq(fused pool+q-relayout) -> ln -> mix(MFMA) -> QKV GEMMs (bf16 MFMA) ->
// batched window attention (flash 2-half, per-wave-private softmax/PV) ->
// out GEMM -> relayout.
// ---------------------------------------------------------------------------

typedef __bf16 bf16;
typedef __bf16 bf16x2 __attribute__((ext_vector_type(2)));
typedef __bf16 bf16x4 __attribute__((ext_vector_type(4)));
typedef __bf16 bf16x8 __attribute__((ext_vector_type(8)));
typedef float f32x4 __attribute__((ext_vector_type(4)));

#define MFMA(a, b, c) __builtin_amdgcn_mfma_f32_16x16x32_bf16(a, b, c, 0, 0, 0)

__device__ __forceinline__ void gll16(const void* g, void* l) {
  __builtin_amdgcn_global_load_lds((const __attribute__((address_space(1))) void*)g,
                                   (__attribute__((address_space(3))) void*)l, 16, 0, 0);
}

// ---------------------------------------------------------------------------
__global__ void k_wconv(const float* __restrict__ in_w, const float* __restrict__ out_w,
                        bf16* __restrict__ wib, bf16* __restrict__ wob) {
  int i = blockIdx.x * blockDim.x + threadIdx.x;
  const int n1 = (1536 * 512) / 4;
  float4 v;
  bf16* dst;
  if (i < n1) { v = ((const float4*)in_w)[i];      dst = wib + (size_t)i * 4; }
  else        { v = ((const float4*)out_w)[i - n1]; dst = wob + (size_t)(i - n1) * 4; }
  dst[0] = (bf16)v.x; dst[1] = (bf16)v.y; dst[2] = (bf16)v.z; dst[3] = (bf16)v.w;
}

// ---------------------------------------------------------------------------
// Fused: read x once -> pooled xp2t[y2][x2][c] fp32 + q relayout bf16.
__global__ __launch_bounds__(256) void k_pq(const float* __restrict__ x,
                                            float* __restrict__ xp2t,
                                            bf16* __restrict__ qb) {
  __shared__ float xs[2][64][133];
  const int y2 = blockIdx.x, c0 = blockIdx.y * 64, t = threadIdx.x;
  #pragma unroll
  for (int it = 0; it < 16; ++it) {
    int flat = it * 256 + t;
    int ci = flat >> 6, rest = flat & 63;
    int yb = rest >> 5, xq = rest & 31;
    float4 v = *(const float4*)(x + (size_t)(c0 + ci) * 16384 +
                                (size_t)(2 * y2 + yb) * 128 + xq * 4);
    float* d = &xs[yb][ci][xq * 4];
    d[0] = v.x; d[1] = v.y; d[2] = v.z; d[3] = v.w;
  }
  __syncthreads();
  #pragma unroll
  for (int it = 0; it < 16; ++it) {
    int flat = it * 256 + t;
    int x2 = flat >> 6, ci = flat & 63;
    float s = xs[0][ci][2 * x2] + xs[0][ci][2 * x2 + 1] +
              xs[1][ci][2 * x2] + xs[1][ci][2 * x2 + 1];
    xp2t[(size_t)(y2 * 64 + x2) * 512 + c0 + ci] = 0.25f * s;
  }
  #pragma unroll
  for (int yb = 0; yb < 2; ++yb) {
    const int Y = 2 * y2 + yb;
    const int hy = Y >> 3, py = Y & 7;
    #pragma unroll
    for (int it = 0; it < 32; ++it) {
      int flat = it * 256 + t;
      int X = flat >> 6, ci = flat & 63;
      int l = py * 8 + (X & 7), s = hy * 16 + (X >> 3);
      qb[((size_t)l * 256 + s) * 512 + c0 + ci] = (bf16)xs[yb][ci][X];
    }
  }
}

// ---------------------------------------------------------------------------
__global__ __launch_bounds__(512) void k_ln(const float* __restrict__ xp2t,
                                            const float* __restrict__ lnw,
                                            const float* __restrict__ lnb,
                                            bf16* __restrict__ T) {
  __shared__ bf16 Tt[512][24];
  const int s = blockIdx.x, qt = blockIdx.y;
  const int wy = s >> 4, wx = s & 15;
  const int t = threadIdx.x, wv = t >> 6, ln = t & 63;

  float wl[8], bl[8];
  #pragma unroll
  for (int k = 0; k < 8; ++k) { wl[k] = lnw[k * 64 + ln]; bl[k] = lnb[k * 64 + ln]; }

  float v[2][8], mu_[2], rs_[2];
  #pragma unroll
  for (int p = 0; p < 2; ++p) {
    const int l = qt * 16 + wv * 2 + p;
    const int py = l >> 3, px = l & 7;
    const int y2 = wy * 4 - 2 + py, x2 = wx * 4 - 2 + px;
    const bool inb = (y2 >= 0) && (y2 < 64) && (x2 >= 0) && (x2 < 64);
    const float* src = xp2t + (size_t)(y2 * 64 + x2) * 512;
    float sum = 0.f, ssq = 0.f;
    #pragma unroll
    for (int k = 0; k < 8; ++k) {
      float xv = 0.f;
      if (inb) xv = src[k * 64 + ln];
      v[p][k] = xv; sum += xv; ssq += xv * xv;
    }
    #pragma unroll
    for (int off = 1; off < 64; off <<= 1) {
      sum += __shfl_xor(sum, off);
      ssq += __shfl_xor(ssq, off);
    }
    float mu = sum * (1.f / 512.f);
    mu_[p] = mu;
    rs_[p] = rsqrtf(ssq * (1.f / 512.f) - mu * mu + 1e-6f);
  }
  #pragma unroll
  for (int k = 0; k < 8; ++k) {
    const int c = k * 64 + ln;
    bf16x2 u;
    u.x = (bf16)((v[0][k] - mu_[0]) * rs_[0] * wl[k] + bl[k]);
    u.y = (bf16)((v[1][k] - mu_[1]) * rs_[1] * wl[k] + bl[k]);
    *(bf16x2*)(&Tt[c][wv * 2]) = u;
  }
  __syncthreads();
  #pragma unroll
  for (int it = 0; it < 2; ++it) {
    int flat = it * 512 + t;
    int c = flat >> 1, ch = flat & 1;
    bf16x8 u = *(const bf16x8*)(&Tt[c][ch * 8]);
    *(bf16x8*)(T + ((size_t)s * 512 + c) * 64 + qt * 16 + ch * 8) = u;
  }
}

// ---------------------------------------------------------------------------
__global__ __launch_bounds__(256) void k_mix(const bf16* __restrict__ T,
                                             const float* __restrict__ mix_w,
                                             const float* __restrict__ mix_b,
                                             bf16* __restrict__ ctx) {
  const int t = threadIdx.x, wv = t >> 6, ln = t & 63;
  const int s = blockIdx.x, hg = blockIdx.y;
  const int h = hg * 4 + wv;
  const int q = ln >> 4, r = ln & 15;

  bf16x8 a[4][2];
  #pragma unroll
  for (int m = 0; m < 4; ++m) {
    #pragma unroll
    for (int ks = 0; ks < 2; ++ks) {
      const int rm = m * 16 + r;
      const float* wsrc = mix_w + ((size_t)h * 64 + rm) * 64 + ks * 32 + q * 8;
      bf16x8 pk;
      #pragma unroll
      for (int e = 0; e < 8; ++e) {
        int l = ks * 32 + q * 8 + e;
        float w = wsrc[e] + (rm == l ? 1.f : 0.f);
        pk[e] = (bf16)w;
      }
      a[m][ks] = pk;
    }
  }
  const bf16* Tb = T + ((size_t)s * 512 + h * 64) * 64;
  bf16x8 b[4][2];
  #pragma unroll
  for (int n = 0; n < 4; ++n) {
    #pragma unroll
    for (int ks = 0; ks < 2; ++ks)
      b[n][ks] = *(const bf16x8*)(Tb + (size_t)(n * 16 + r) * 64 + ks * 32 + q * 8);
  }
  f32x4 acc[4][4] = {};
  #pragma unroll
  for (int ks = 0; ks < 2; ++ks) {
    #pragma unroll
    for (int m = 0; m < 4; ++m) {
      #pragma unroll
      for (int n = 0; n < 4; ++n) acc[m][n] = MFMA(a[m][ks], b[n][ks], acc[m][n]);
    }
  }
  #pragma unroll
  for (int m = 0; m < 4; ++m) {
    #pragma unroll
    for (int j = 0; j < 4; ++j) {
      const int rm = m * 16 + q * 4 + j;
      const float bias = mix_b[h * 64 + rm];
      #pragma unroll
      for (int n = 0; n < 4; ++n)
        ctx[((size_t)rm * 256 + s) * 512 + h * 64 + n * 16 + r] =
            (bf16)(acc[m][n][j] + bias);
    }
  }
}

// ---------------------------------------------------------------------------
// GEMM C[M,N] = A[M,K=512] @ B[N,K=512]^T + bias, bf16 in, fp32 accum.
template <int MODE>
__global__ __launch_bounds__(256, 4) void k_gemm(const bf16* __restrict__ A,
                                                 const bf16* __restrict__ B,
                                                 const float* __restrict__ bias,
                                                 bf16* __restrict__ O0,
                                                 bf16* __restrict__ O1) {
  __shared__ bf16 As[8192];
  __shared__ bf16 Bs[8192];
  const int t = threadIdx.x, wv = t >> 6, ln = t & 63;
  const int bm = blockIdx.x, bn = blockIdx.y;
  const int wm = wv >> 1, wn = wv & 1;
  const int q = ln >> 4, r = ln & 15;
  f32x4 acc[4][4] = {};

  const int srow = wv * 8 + (ln >> 3);
  const int swzc = (ln & 7) ^ (ln >> 3);
  const char* ga = (const char*)A + ((size_t)(bm * 128 + srow) * 512) * 2 + swzc * 16;
  const char* gb = (const char*)B + ((size_t)(bn * 128 + srow) * 512) * 2 + swzc * 16;

  for (int k0 = 0; k0 < 512; k0 += 64) {
    #pragma unroll
    for (int i = 0; i < 4; ++i) {
      gll16(ga + (size_t)i * 32 * 1024 + k0 * 2, As + i * 2048 + wv * 512);
      gll16(gb + (size_t)i * 32 * 1024 + k0 * 2, Bs + i * 2048 + wv * 512);
    }
    __syncthreads();
    #pragma unroll
    for (int ks = 0; ks < 2; ++ks) {
      bf16x8 af[4], bfr[4];
      #pragma unroll
      for (int m = 0; m < 4; ++m)
        af[m] = *(const bf16x8*)(As + (wm * 64 + m * 16 + r) * 64 +
                                 (((ks * 4 + q) ^ (r & 7)) * 8));
      #pragma unroll
      for (int n = 0; n < 4; ++n)
        bfr[n] = *(const bf16x8*)(Bs + (wn * 64 + n * 16 + r) * 64 +
                                  (((ks * 4 + q) ^ (r & 7)) * 8));
      #pragma unroll
      for (int m = 0; m < 4; ++m) {
        #pragma unroll
        for (int n = 0; n < 4; ++n) acc[m][n] = MFMA(af[m], bfr[n], acc[m][n]);
      }
    }
    __syncthreads();
  }

  const int r0 = bm * 128 + wm * 64 + q * 4;
  const int c0 = bn * 128 + wn * 64 + r;
  #pragma unroll
  for (int m = 0; m < 4; ++m) {
    const int rg0 = r0 + m * 16;
    #pragma unroll
    for (int n = 0; n < 4; ++n) {
      const int cg = c0 + n * 16;
      const float bv = bias[cg];
      if constexpr (MODE == 2) {
        #pragma unroll
        for (int j = 0; j < 4; ++j)
          O0[(size_t)(rg0 + j) * 512 + cg] = (bf16)(acc[m][n][j] + bv);
      } else if constexpr (MODE == 0) {
        const int li = rg0 >> 8;
        #pragma unroll
        for (int j = 0; j < 4; ++j) {
          int sp = (rg0 + j) & 255;
          O0[(((size_t)li * 8 + (cg >> 6)) * 256 + sp) * 64 + (cg & 63)] =
              (bf16)(acc[m][n][j] + bv);
        }
      } else {  // MODE 1
        const int li = rg0 >> 8;
        if (cg < 512) {
          #pragma unroll
          for (int j = 0; j < 4; ++j) {
            int sp = (rg0 + j) & 255;
            O0[(((size_t)li * 8 + (cg >> 6)) * 256 + sp) * 64 + (cg & 63)] =
                (bf16)(acc[m][n][j] + bv);
          }
        } else {
          const int e = cg - 512, hh = e >> 6, d = e & 63;
          const int sp = rg0 & 255;
          bf16x4 pk;
          #pragma unroll
          for (int j = 0; j < 4; ++j) pk[j] = (bf16)(acc[m][n][j] + bv);
          *(bf16x4*)(&O1[(((size_t)li * 8 + hh) * 64 + d) * 256 + sp]) = pk;
        }
      }
    }
  }
}

// ---------------------------------------------------------------------------
// Attention per (l,h,s-tile 64), flash over t in 2 halves of 128.
// Wave-private: wave wv owns s-rows wv*16..+15 end-to-end (QK^T, softmax,
// PV over all 64 d). Stats per-lane. P handoff via per-wave LDS buffer
// (no cross-wave barrier). K staged by global_load_lds with XOR swizzle.
// Barriers: 3 total (K0 ready / K-h0 reads done / K1 ready).
__global__ __launch_bounds__(256, 4) void k_attn(const bf16* __restrict__ Qa,
                                                 const bf16* __restrict__ Ka,
                                                 const bf16* __restrict__ Vt,
                                                 bf16* __restrict__ Oa) {
  __shared__ bf16 Ks[128 * 64];      // 16 KB, linear (source pre-swizzled)
  __shared__ bf16 Pw[4][16][132];    // 16.9 KB, per-wave private
  const int t = threadIdx.x, wv = t >> 6, ln = t & 63;
  const int q = ln >> 4, r = ln & 15;
  const int bid = blockIdx.x;
  const int st = (bid >> 3) & 3;                 // siblings share bid%8 -> XCD
  const int lh = (bid & 7) | ((bid >> 5) << 3);
  const int s0 = st * 64;
  const size_t base = (size_t)lh * (256 * 64);
  const bf16* __restrict__ Qlh = Qa + base;
  const bf16* __restrict__ Klh = Ka + base;
  const bf16* __restrict__ Vlh = Vt + base;
  const float SC = 0.125f * 1.4426950408889634f;

  // Q A-frags for this wave's 16 rows
  bf16x8 aq[2];
  #pragma unroll
  for (int ks = 0; ks < 2; ++ks)
    aq[ks] = *(const bf16x8*)(Qlh + (size_t)(s0 + wv * 16 + r) * 64 + ks * 32 + q * 8);

  // K staging geometry (gll16, XOR-swizzled source; K row = 128 B)
  const int srow = wv * 8 + (ln >> 3);
  const int swzc = (ln & 7) ^ (ln >> 3);
  const char* gk = (const char*)Klh + srow * 128 + swzc * 16;
  #pragma unroll
  for (int i = 0; i < 4; ++i)
    gll16(gk + i * 4096, Ks + i * 2048 + wv * 512);
  __syncthreads();                               // sync1: K half0 ready

  f32x4 ao[4] = {};
  float mrun[4], lrun[4];

  #pragma unroll
  for (int h = 0; h < 2; ++h) {
    // QK^T: sa[n] rows = own s, cols t = n*16 + r (within this half)
    f32x4 sa[8];
    #pragma unroll
    for (int n = 0; n < 8; ++n) sa[n] = (f32x4){0.f, 0.f, 0.f, 0.f};
    __builtin_amdgcn_s_setprio(1);
    #pragma unroll
    for (int n = 0; n < 8; ++n) {
      const bf16* kr = Ks + (n * 16 + r) * 64;
      bf16x8 b0 = *(const bf16x8*)(kr + ((q ^ (r & 7)) * 8));
      bf16x8 b1 = *(const bf16x8*)(kr + (((4 + q) ^ (r & 7)) * 8));
      sa[n] = MFMA(aq[0], b0, sa[n]);
      sa[n] = MFMA(aq[1], b1, sa[n]);
    }
    __builtin_amdgcn_s_setprio(0);

    if (h == 0) {
      __syncthreads();                           // sync2: all done reading K0
      #pragma unroll
      for (int i = 0; i < 4; ++i)
        gll16(gk + 16384 + i * 4096, Ks + i * 2048 + wv * 512);  // K half1 in flight
    }

    // per-lane softmax for rows q*4+j (reduce over n in-lane + r-butterfly)
    #pragma unroll
    for (int j = 0; j < 4; ++j) {
      float mx = sa[0][j];
      #pragma unroll
      for (int n = 1; n < 8; ++n) mx = fmaxf(mx, sa[n][j]);
      #pragma unroll
      for (int off = 1; off < 16; off <<= 1) mx = fmaxf(mx, __shfl_xor(mx, off));
      float mnew = (h == 0) ? mx : fmaxf(mrun[j], mx);
      const float mb = mnew * SC;
      float sm = 0.f;
      #pragma unroll
      for (int n = 0; n < 8; ++n) {
        float p = exp2f(sa[n][j] * SC - mb);
        sa[n][j] = p;
        sm += p;
      }
      #pragma unroll
      for (int off = 1; off < 16; off <<= 1) sm += __shfl_xor(sm, off);
      if (h == 0) {
        mrun[j] = mnew; lrun[j] = sm;
      } else {
        float scale = exp2f(mrun[j] * SC - mb);
        lrun[j] = lrun[j] * scale + sm;
        #pragma unroll
        for (int n = 0; n < 4; ++n) ao[n][j] *= scale;
      }
    }

    // P -> per-wave LDS (row = own s-local, col = t)
    #pragma unroll
    for (int n = 0; n < 8; ++n) {
      #pragma unroll
      for (int j = 0; j < 4; ++j)
        Pw[wv][q * 4 + j][n * 16 + r] = (bf16)sa[n][j];
    }
    // read back A-frags (same wave; in-order DS, no barrier)
    bf16x8 pa[4];
    #pragma unroll
    for (int ks = 0; ks < 4; ++ks)
      pa[ks] = *(const bf16x8*)(&Pw[wv][r][ks * 32 + q * 8]);

    // PV: O[own 16 s][64 d] += P[16 x 128] V[128 x 64]
    __builtin_amdgcn_s_setprio(1);
    #pragma unroll
    for (int ks = 0; ks < 4; ++ks) {
      #pragma unroll
      for (int n = 0; n < 4; ++n) {
        bf16x8 vf = *(const bf16x8*)(Vlh + (size_t)(n * 16 + r) * 256 +
                                     h * 128 + ks * 32 + q * 8);
        ao[n] = MFMA(pa[ks], vf, ao[n]);
      }
    }
    __builtin_amdgcn_s_setprio(0);

    if (h == 0) __syncthreads();                 // sync3: K half1 ready
  }

  // epilogue: per-lane 1/l scale, scalar bf16 stores (rows own, d = n*16+r)
  float rr[4];
  #pragma unroll
  for (int j = 0; j < 4; ++j) rr[j] = 1.f / lrun[j];
  bf16* dst = Oa + ((size_t)(lh >> 3) * 256 + s0 + wv * 16 + q * 4) * 512 +
              (lh & 7) * 64 + r;
  #pragma unroll
  for (int j = 0; j < 4; ++j) {
    #pragma unroll
    for (int n = 0; n < 4; ++n)
      dst[(size_t)j * 512 + n * 16] = (bf16)(ao[n][j] * rr[j]);
  }
}

// ---------------------------------------------------------------------------
__global__ void k_orelay(const bf16* __restrict__ o_tmp, float* __restrict__ out) {
  __shared__ bf16 buf[64][130];
  const int hy = blockIdx.x, py = blockIdx.y, e0 = blockIdx.z * 64, t = threadIdx.x;
  #pragma unroll
  for (int i = 0; i < 32; ++i) {
    int flat = i * 256 + t;
    int r = flat >> 6, e = flat & 63;
    int px = r >> 4, hx = r & 15;
    buf[e][hx * 8 + px] =
        o_tmp[((size_t)(py * 8 + px) * 256 + hy * 16 + hx) * 512 + e0 + e];
  }
  __syncthreads();
  const int Y = hy * 8 + py;
  #pragma unroll
  for (int i = 0; i < 32; ++i) {
    int flat = i * 256 + t;
    int e = flat >> 7, X = flat & 127;
    out[(size_t)(e0 + e) * 16384 + (size_t)Y * 128 + X] = (float)buf[e][X];
  }
}

// ---------------------------------------------------------------------------
extern "C" void kernel_launch(void* const* d_in, const int* in_sizes, int n_in,
                              void* d_out, int out_size, void* d_ws, size_t ws_size,
                              hipStream_t stream) {
  const float* x     = (const float*)d_in[0];
  const float* ln_w  = (const float*)d_in[1];
  const float* ln_b  = (const float*)d_in[2];
  const float* mix_w = (const float*)d_in[3];
  const float* mix_b = (const float*)d_in[4];
  const float* in_w  = (const float*)d_in[5];
  const float* in_b  = (const float*)d_in[6];
  const float* out_w = (const float*)d_in[7];
  const float* out_b = (const float*)d_in[8];
  float* out = (float*)d_out;
  char* ws = (char*)d_ws;

  const size_t MB = 1u << 20;
  float* xp2t = (float*)(ws);                    // [0,8)   pq -> ln
  bf16* qb    = (bf16*)(ws + 8 * MB);            // [8,24)  pq -> gemm0
  bf16* Tn    = (bf16*)(ws + 24 * MB);           // [24,40) ln -> mix
  bf16* ctxb  = (bf16*)(ws + 40 * MB);           // [40,56) mix -> gemm1
  bf16* Qa    = (bf16*)(ws + 56 * MB);           // [56,72) gemm0 -> attn
  bf16* Ka    = (bf16*)(ws);                     // [0,16)  gemm1 -> attn
  bf16* Vt    = (bf16*)(ws + 16 * MB);           // [16,32) gemm1 -> attn
  bf16* oatt  = (bf16*)(ws + 32 * MB);           // [32,48) attn -> gemm2
  bf16* otmp  = (bf16*)(ws + 48 * MB);           // [48,64) gemm2 -> orelay
  bf16* wib   = (bf16*)(ws + 72 * MB);
  bf16* wob   = (bf16*)(ws + 72 * MB + 1572864);

  k_wconv<<<1024, 256, 0, stream>>>(in_w, out_w, wib, wob);
  k_pq<<<dim3(64, 8), 256, 0, stream>>>(x, xp2t, qb);
  k_ln<<<dim3(256, 4), 512, 0, stream>>>(xp2t, ln_w, ln_b, Tn);
  k_mix<<<dim3(256, 2), 256, 0, stream>>>(Tn, mix_w, mix_b, ctxb);
  k_gemm<0><<<dim3(128, 4), 256, 0, stream>>>(qb, wib, in_b, Qa, nullptr);
  k_gemm<1><<<dim3(128, 8), 256, 0, stream>>>(ctxb, wib + 512 * 512, in_b + 512, Ka, Vt);
  k_attn<<<2048, 256, 0, stream>>>(Qa, Ka, Vt, oatt);
  k_gemm<2><<<dim3(128, 4), 256, 0, stream>>>(oatt, wob, out_b, otmp, nullptr);
  k_orelay<<<dim3(16, 8, 8), 256, 0, stream>>>(otmp, out);
}